// Round 1
// baseline (961.360 us; speedup 1.0000x reference)
//
#include <hip/hip_runtime.h>

#define LOG2E   1.4426950408889634f
#define QKSCALE 0.044194173824159216f   // 1/sqrt(512)

typedef __attribute__((ext_vector_type(4))) float  f32x4;
typedef __attribute__((ext_vector_type(8))) __bf16 bf16x8;
typedef __attribute__((ext_vector_type(4))) __bf16 bf16x4;

static __device__ __forceinline__ f32x4 mfma16(bf16x8 a, bf16x8 b, f32x4 c) {
  return __builtin_amdgcn_mfma_f32_16x16x32_bf16(a, b, c, 0, 0, 0);
}

// ---------------------------------------------------------------------------
// memory [16][2048][512] f32  ->  memT [16][512][2048] bf16
__global__ __launch_bounds__(256)
void k_transpose(const float* __restrict__ mem, __bf16* __restrict__ mbT) {
  __shared__ float t[32][33];
  const int b  = blockIdx.z;
  const int m0 = blockIdx.y * 32;
  const int d0 = blockIdx.x * 32;
  const int tx = threadIdx.x, ty = threadIdx.y;
  const float* src = mem + ((size_t)b * 2048 + m0) * 512 + d0;
#pragma unroll
  for (int r = 0; r < 4; ++r)
    t[ty + r * 8][tx] = src[(size_t)(ty + r * 8) * 512 + tx];
  __syncthreads();
  __bf16* dst = mbT + ((size_t)b * 512 + d0) * 2048 + m0;
#pragma unroll
  for (int r = 0; r < 4; ++r)
    dst[(size_t)(ty + r * 8) * 2048 + tx] = (__bf16)t[tx][ty + r * 8];
}

// ---------------------------------------------------------------------------
// C[M x N] = relu(A[M x K] * W[N x K]^T), f32 in, bf16 out.  128x128 tile, BK=32.
__global__ __launch_bounds__(256, 2)
void k_gemm_relu(const float* __restrict__ A, const float* __restrict__ W,
                 __bf16* __restrict__ C, const int K, const int N) {
  const int tid = threadIdx.x;
  const int wid = tid >> 6, l = tid & 63, lg = l >> 4, lc = l & 15;
  const int wr = wid >> 1, wc = wid & 1;
  const int row0 = blockIdx.y * 128, col0 = blockIdx.x * 128;
  __shared__ __bf16 As[128 * 32];
  __shared__ __bf16 Bs[128 * 32];

  f32x4 acc[4][4];
#pragma unroll
  for (int mi = 0; mi < 4; ++mi)
#pragma unroll
    for (int ni = 0; ni < 4; ++ni) acc[mi][ni] = (f32x4){0.f, 0.f, 0.f, 0.f};

  f32x4 ra[4], rb[4];
  auto loadT = [&](int kt) {
    const int k0 = kt << 5;
#pragma unroll
    for (int i = 0; i < 4; ++i) {
      const int c = tid + i * 256;
      ra[i] = *(const f32x4*)(A + (size_t)(row0 + (c >> 3)) * K + k0 + ((c & 7) << 2));
      rb[i] = *(const f32x4*)(W + (size_t)(col0 + (c >> 3)) * K + k0 + ((c & 7) << 2));
    }
  };

  loadT(0);
  const int NT = K >> 5;
#pragma unroll 1
  for (int kt = 0; kt < NT; ++kt) {
    __syncthreads();
#pragma unroll
    for (int i = 0; i < 4; ++i) {
      const int c = tid + i * 256;
      bf16x4 va, vb;
#pragma unroll
      for (int j = 0; j < 4; ++j) { va[j] = (__bf16)ra[i][j]; vb[j] = (__bf16)rb[i][j]; }
      *(bf16x4*)(&As[(c >> 3) * 32 + ((c & 7) << 2)]) = va;
      *(bf16x4*)(&Bs[(c >> 3) * 32 + ((c & 7) << 2)]) = vb;
    }
    __syncthreads();
    if (kt + 1 < NT) loadT(kt + 1);

    bf16x8 af[4], bfr[4];
#pragma unroll
    for (int mi = 0; mi < 4; ++mi)
      af[mi] = *(const bf16x8*)(&As[(wr * 64 + mi * 16 + lc) * 32 + (lg << 3)]);
#pragma unroll
    for (int ni = 0; ni < 4; ++ni)
      bfr[ni] = *(const bf16x8*)(&Bs[(wc * 64 + ni * 16 + lc) * 32 + (lg << 3)]);
#pragma unroll
    for (int mi = 0; mi < 4; ++mi)
#pragma unroll
      for (int ni = 0; ni < 4; ++ni)
        acc[mi][ni] = mfma16(af[mi], bfr[ni], acc[mi][ni]);
  }

#pragma unroll
  for (int mi = 0; mi < 4; ++mi)
#pragma unroll
    for (int ni = 0; ni < 4; ++ni)
#pragma unroll
      for (int r = 0; r < 4; ++r) {
        float v = acc[mi][ni][r];
        v = v > 0.f ? v : 0.f;
        C[(size_t)(row0 + wr * 64 + mi * 16 + lg * 4 + r) * N +
          (col0 + wc * 64 + ni * 16 + lc)] = (__bf16)v;
      }
}

// ---------------------------------------------------------------------------
// Flash attention. hI,hM: [16][2048][512] bf16; mbT: [16][512][2048] bf16;
// mask: [16][2048] int; att out: [16][2048][512] bf16.
// 512 threads = 8 waves, each wave owns 16 Q rows; KV tile = 32 rows.
__global__ __launch_bounds__(512, 2)
void k_attn(const __bf16* __restrict__ hI, const __bf16* __restrict__ hM,
            const __bf16* __restrict__ mbT, const int* __restrict__ mask,
            __bf16* __restrict__ att) {
  const int tid = threadIdx.x;
  const int w  = tid >> 6;
  const int l  = tid & 63;
  const int lg = l >> 4, lc = l & 15;
  const int b  = blockIdx.x >> 4;
  const int i0 = (blockIdx.x & 15) << 7;
  const int ri = i0 + (w << 4);

  __shared__ __bf16 Ks[32 * 512];     // [m][k], 16B-chunk XOR-swizzled by row&7
  __shared__ __bf16 Vs[512 * 32];     // [d][m], 16B-chunk XOR-swizzled by d&3
  __shared__ __bf16 Ps[8][16][56];    // per-wave P tile, stride 56 (112B, 16B-aligned)

  bf16x8 q[16];
  {
    const __bf16* qb = hI + ((size_t)(b * 2048) + ri + lc) * 512;
#pragma unroll
    for (int kk = 0; kk < 16; ++kk) q[kk] = *(const bf16x8*)(qb + kk * 32 + (lg << 3));
  }
  f32x4 accO[32];
#pragma unroll
  for (int dt = 0; dt < 32; ++dt) accO[dt] = (f32x4){0.f, 0.f, 0.f, 0.f};
  float mrow[4], lrow[4];
#pragma unroll
  for (int r = 0; r < 4; ++r) { mrow[r] = -__builtin_inff(); lrow[r] = 0.f; }

  const __bf16* ksrc = hM + (size_t)(b * 2048) * 512;
  const __bf16* vsrc = mbT + (size_t)(b * 512) * 2048;
  const int* mbase = mask + b * 2048;

#pragma unroll 1
  for (int step = 0; step < 64; ++step) {
    const int m0 = step << 5;
    bf16x8 kv[4], vv[4];
#pragma unroll
    for (int i = 0; i < 4; ++i) {
      const int c = tid + (i << 9);
      kv[i] = *(const bf16x8*)(ksrc + (size_t)(m0 + (c >> 6)) * 512 + ((c & 63) << 3));
    }
#pragma unroll
    for (int i = 0; i < 4; ++i) {
      const int c = tid + (i << 9);
      vv[i] = *(const bf16x8*)(vsrc + (size_t)(c >> 2) * 2048 + m0 + ((c & 3) << 3));
    }
    const int mv0 = mbase[m0 + lc];
    const int mv1 = mbase[m0 + 16 + lc];
    __syncthreads();   // previous step's LDS reads done
#pragma unroll
    for (int i = 0; i < 4; ++i) {
      const int c = tid + (i << 9);
      const int row = c >> 6, cb = c & 63;
      *(bf16x8*)(&Ks[row * 512 + ((cb ^ (row & 7)) << 3)]) = kv[i];
    }
#pragma unroll
    for (int i = 0; i < 4; ++i) {
      const int c = tid + (i << 9);
      const int d = c >> 2, cb = c & 3;
      *(bf16x8*)(&Vs[(d << 5) + ((cb ^ (d & 3)) << 3)]) = vv[i];
    }
    __syncthreads();   // tiles visible

    // QK^T : S[16 x 32] per wave
    f32x4 s0 = {0.f, 0.f, 0.f, 0.f}, s1 = {0.f, 0.f, 0.f, 0.f};
#pragma unroll
    for (int kk = 0; kk < 16; ++kk) {
      const int cb = (kk << 2) + lg;
      bf16x8 kf0 = *(const bf16x8*)(&Ks[lc * 512 + ((cb ^ (lc & 7)) << 3)]);
      bf16x8 kf1 = *(const bf16x8*)(&Ks[(16 + lc) * 512 + ((cb ^ (lc & 7)) << 3)]);
      s0 = mfma16(q[kk], kf0, s0);
      s1 = mfma16(q[kk], kf1, s1);
    }
    // masked online softmax; row i = lg*4 + r, col m = (msub)*16 + lc
    float p0[4], p1[4], alpha[4];
#pragma unroll
    for (int r = 0; r < 4; ++r) {
      const float a = mv0 ? s0[r] * QKSCALE : -1e30f;
      const float c = mv1 ? s1[r] * QKSCALE : -1e30f;
      float t = fmaxf(a, c);
      t = fmaxf(t, __shfl_xor(t, 1));
      t = fmaxf(t, __shfl_xor(t, 2));
      t = fmaxf(t, __shfl_xor(t, 4));
      t = fmaxf(t, __shfl_xor(t, 8));
      const float mn = fmaxf(mrow[r], t);
      alpha[r] = exp2f((mrow[r] - mn) * LOG2E);
      mrow[r] = mn;
      p0[r] = exp2f((a - mn) * LOG2E);
      p1[r] = exp2f((c - mn) * LOG2E);
      float rs = p0[r] + p1[r];
      rs += __shfl_xor(rs, 1);
      rs += __shfl_xor(rs, 2);
      rs += __shfl_xor(rs, 4);
      rs += __shfl_xor(rs, 8);
      lrow[r] = lrow[r] * alpha[r] + rs;
    }
#pragma unroll
    for (int dt = 0; dt < 32; ++dt) {
#pragma unroll
      for (int r = 0; r < 4; ++r) accO[dt][r] *= alpha[r];
    }
    // P -> LDS (bf16), then read back as A-fragment
#pragma unroll
    for (int r = 0; r < 4; ++r) {
      Ps[w][(lg << 2) + r][lc]      = (__bf16)p0[r];
      Ps[w][(lg << 2) + r][16 + lc] = (__bf16)p1[r];
    }
    const bf16x8 pa = *(const bf16x8*)(&Ps[w][lc][lg << 3]);
    // PV: O[16 x 512] accumulate
#pragma unroll
    for (int dt = 0; dt < 32; ++dt) {
      const int d = (dt << 4) + lc;
      bf16x8 vf = *(const bf16x8*)(&Vs[(d << 5) + ((lg ^ (d & 3)) << 3)]);
      accO[dt] = mfma16(pa, vf, accO[dt]);
    }
  }
  // epilogue: normalize, store bf16
  __bf16* ob = att + ((size_t)(b * 2048) + ri) * 512;
#pragma unroll
  for (int dt = 0; dt < 32; ++dt) {
#pragma unroll
    for (int r = 0; r < 4; ++r) {
      const float o = accO[dt][r] / lrow[r];
      ob[(size_t)((lg << 2) + r) * 512 + (dt << 4) + lc] = (__bf16)o;
    }
  }
}

// ---------------------------------------------------------------------------
// gate GEMM: res = [inputs | att] (K=1024), gate = sigmoid(res * W_res^T),
// out = res * gate (f32).  128x128 tile, BK=32.
__global__ __launch_bounds__(256, 2)
void k_gemm_gate(const float* __restrict__ inputs, const __bf16* __restrict__ att,
                 const float* __restrict__ W, float* __restrict__ out) {
  const int tid = threadIdx.x;
  const int wid = tid >> 6, l = tid & 63, lg = l >> 4, lc = l & 15;
  const int wr = wid >> 1, wc = wid & 1;
  const int row0 = blockIdx.y * 128, col0 = blockIdx.x * 128;
  __shared__ __bf16 As[128 * 32];
  __shared__ __bf16 Bs[128 * 32];

  f32x4 acc[4][4];
#pragma unroll
  for (int mi = 0; mi < 4; ++mi)
#pragma unroll
    for (int ni = 0; ni < 4; ++ni) acc[mi][ni] = (f32x4){0.f, 0.f, 0.f, 0.f};

  f32x4 raf[4]; bf16x8 rab[2]; f32x4 rw[4];
  auto loadT = [&](int kt) {
    if (kt < 16) {
      const int k0 = kt << 5;
#pragma unroll
      for (int i = 0; i < 4; ++i) {
        const int c = tid + i * 256;
        raf[i] = *(const f32x4*)(inputs + (size_t)(row0 + (c >> 3)) * 512 + k0 + ((c & 7) << 2));
      }
    } else {
      const int k0 = (kt - 16) << 5;
#pragma unroll
      for (int i = 0; i < 2; ++i) {
        const int c = tid + i * 256;
        rab[i] = *(const bf16x8*)(att + (size_t)(row0 + (c >> 2)) * 512 + k0 + ((c & 3) << 3));
      }
    }
    const int k0w = kt << 5;
#pragma unroll
    for (int i = 0; i < 4; ++i) {
      const int c = tid + i * 256;
      rw[i] = *(const f32x4*)(W + (size_t)(col0 + (c >> 3)) * 1024 + k0w + ((c & 7) << 2));
    }
  };

  loadT(0);
#pragma unroll 1
  for (int kt = 0; kt < 32; ++kt) {
    __syncthreads();
    if (kt < 16) {
#pragma unroll
      for (int i = 0; i < 4; ++i) {
        const int c = tid + i * 256;
        bf16x4 va;
#pragma unroll
        for (int j = 0; j < 4; ++j) va[j] = (__bf16)raf[i][j];
        *(bf16x4*)(&As[(c >> 3) * 32 + ((c & 7) << 2)]) = va;
      }
    } else {
#pragma unroll
      for (int i = 0; i < 2; ++i) {
        const int c = tid + i * 256;
        *(bf16x8*)(&As[(c >> 2) * 32 + ((c & 3) << 3)]) = rab[i];
      }
    }
#pragma unroll
    for (int i = 0; i < 4; ++i) {
      const int c = tid + i * 256;
      bf16x4 vb;
#pragma unroll
      for (int j = 0; j < 4; ++j) vb[j] = (__bf16)rw[i][j];
      *(bf16x4*)(&Bs[(c >> 3) * 32 + ((c & 7) << 2)]) = vb;
    }
    __syncthreads();
    if (kt + 1 < 32) loadT(kt + 1);

    bf16x8 af[4], bfr[4];
#pragma unroll
    for (int mi = 0; mi < 4; ++mi)
      af[mi] = *(const bf16x8*)(&As[(wr * 64 + mi * 16 + lc) * 32 + (lg << 3)]);
#pragma unroll
    for (int ni = 0; ni < 4; ++ni)
      bfr[ni] = *(const bf16x8*)(&Bs[(wc * 64 + ni * 16 + lc) * 32 + (lg << 3)]);
#pragma unroll
    for (int mi = 0; mi < 4; ++mi)
#pragma unroll
      for (int ni = 0; ni < 4; ++ni)
        acc[mi][ni] = mfma16(af[mi], bfr[ni], acc[mi][ni]);
  }

#pragma unroll
  for (int mi = 0; mi < 4; ++mi)
#pragma unroll
    for (int ni = 0; ni < 4; ++ni) {
      const int gcol = col0 + wc * 64 + ni * 16 + lc;
#pragma unroll
      for (int r = 0; r < 4; ++r) {
        const int grow = row0 + wr * 64 + mi * 16 + lg * 4 + r;
        const float v = acc[mi][ni][r];
        const float g = 1.f / (1.f + exp2f(-v * LOG2E));
        const float resv = (gcol < 512)
            ? inputs[(size_t)grow * 512 + gcol]
            : (float)att[(size_t)grow * 512 + (gcol - 512)];
        out[(size_t)grow * 1024 + gcol] = resv * g;
      }
    }
}

// ---------------------------------------------------------------------------
extern "C" void kernel_launch(void* const* d_in, const int* in_sizes, int n_in,
                              void* d_out, int out_size, void* d_ws, size_t ws_size,
                              hipStream_t stream) {
  (void)in_sizes; (void)n_in; (void)out_size; (void)ws_size;
  const float* inputs = (const float*)d_in[0];
  const float* memory = (const float*)d_in[1];
  const int*   mask   = (const int*)d_in[2];
  const float* W_in   = (const float*)d_in[3];
  const float* W_mem  = (const float*)d_in[4];
  const float* W_res  = (const float*)d_in[5];
  float* out = (float*)d_out;

  char* ws = (char*)d_ws;
  __bf16* mbT = (__bf16*)(ws);                        // 32 MB [16][512][2048]
  __bf16* hI  = (__bf16*)(ws + ((size_t)32 << 20));   // 32 MB [16][2048][512]
  __bf16* hM  = (__bf16*)(ws + ((size_t)64 << 20));   // 32 MB
  __bf16* att = (__bf16*)(ws + ((size_t)96 << 20));   // 32 MB

  k_transpose<<<dim3(16, 64, 16), dim3(32, 8), 0, stream>>>(memory, mbT);
  k_gemm_relu<<<dim3(4, 256), 256, 0, stream>>>(inputs, W_in, hI, 512, 512);
  k_gemm_relu<<<dim3(4, 256), 256, 0, stream>>>(memory, W_mem, hM, 512, 512);
  k_attn<<<dim3(256), 512, 0, stream>>>(hI, hM, mbT, mask, att);
  k_gemm_gate<<<dim3(8, 256), 256, 0, stream>>>(inputs, att, W_res, out);
}